// Round 6
// baseline (952.868 us; speedup 1.0000x reference)
//
#include <hip/hip_runtime.h>

namespace {

constexpr int NX = 384, NY = 384, NZ = 48;
constexpr int NXU = NX + 1;
constexpr int PLN = NX * NY;
constexpr float RDX = 1.0f / 1000.0f;
constexpr float RDY = 1.0f / 1000.0f;
constexpr float RDZ = 49.0f;              // 1/DZ, DZ = 1/(NZ+1)
constexpr float PREF = 100000.0f, RD = 287.0f, G = 9.81f;
constexpr float K_RP = RD / PREF;

constexpr int SZ_U = NZ * NY * NXU;
constexpr int SZ_V = NZ * (NY + 1) * NX;
constexpr int SZ_W = (NZ - 1) * PLN;
constexpr int SZ_T = NZ * PLN;
constexpr int SZ_M = NZ * PLN;
constexpr int SZ_P = (NZ - 1) * PLN;

// tile geometry
constexpr int TX = 32, TY = 8;            // 256 threads
constexpr int PW = TX + 3;                // 35 (cols i0-1 .. i0+33)
constexpr int PH = TY + 3;                // 11 (rows j0-1 .. j0+9)
constexpr int PSZ = PW * PH;              // 385
constexpr int KCH = 12, KSPLIT = 4;

struct Idx { int pix, uo, vo, pxa, pxb, pya, pyb; };
struct Raw { float ph, phm, ph1, mu, mu1, tht, Uv, Vv, Wv, mxa, mxb, mya, myb; };

__device__ __forceinline__ float frcp(float x) { return __builtin_amdgcn_rcpf(x); }
__device__ __forceinline__ float pow14(float x) {
    return __builtin_amdgcn_exp2f(1.4f * __builtin_amdgcn_logf(x));   // x^1.4 (log/exp are base-2)
}

__global__ __launch_bounds__(256, 4)
void rhs_tile(
    const float* __restrict__ Us, const float* __restrict__ Vs, const float* __restrict__ Ws,
    const float* __restrict__ Ts, const float* __restrict__ Ms, const float* __restrict__ Ps,
    const float* __restrict__ Phit, const float* __restrict__ Phis,
    const float* __restrict__ Pt,   const float* __restrict__ Psrf,
    const float* __restrict__ U0, const float* __restrict__ V0, const float* __restrict__ W0,
    const float* __restrict__ T0, const float* __restrict__ M0, const float* __restrict__ P0,
    float* __restrict__ Uo, float* __restrict__ Vo, float* __restrict__ Wo,
    float* __restrict__ To, float* __restrict__ Mo, float* __restrict__ Po,
    const int* __restrict__ dtp, float coef)
{
    const int tx = threadIdx.x, ty = threadIdx.y;
    const int tid = ty * TX + tx;
    const int i0 = blockIdx.x * TX;
    const int j0 = blockIdx.y * TY;
    const int k0 = blockIdx.z * KCH;
    const int i = i0 + tx, j = j0 + ty;
    const float c = coef * (float)(*dtp);
    const int ly = ty + 1, lx = tx + 1;

    // rings: 3-deep for p / Phi-pad / Omega; 2-deep for the rest
    __shared__ float sPH[3][PSZ], sP[3][PSZ], sOM[3][PSZ];
    __shared__ float sMU[2][PSZ], sTH[2][PSZ], sUR[2][PSZ], su_[2][PSZ],
                     sVR[2][PSZ], sv_[2][PSZ], sw_[2][PSZ];

    // ---- per-thread plane points (tid and tid+256) ----
    auto mkidx = [&](int idx, Idx& q) {
        const int r  = idx / PW;
        const int cc = idx - r * PW;
        int gj = j0 - 1 + r;  if (gj < 0) gj += NY; else if (gj >= NY) gj -= NY;
        int gi = i0 - 1 + cc; if (gi < 0) gi += NX; else if (gi >= NX) gi -= NX;
        int gII = i0 - 1 + cc; if (gII < 0) gII += NX + 1; else if (gII > NX) gII -= NX + 1;
        int gJJ = j0 - 1 + r;  if (gJJ < 0) gJJ += NY + 1; else if (gJJ > NY) gJJ -= NY + 1;
        q.pix = gj * NX + gi;
        q.uo  = gj * NXU + gII;
        q.vo  = gJJ * NX + gi;
        const int xa = (gII == 0)  ? NX - 1 : gII - 1;
        const int xb = (gII == NX) ? 0      : gII;
        const int ya = (gJJ == 0)  ? NY - 1 : gJJ - 1;
        const int yb = (gJJ == NY) ? 0      : gJJ;
        q.pxa = gj * NX + xa; q.pxb = gj * NX + xb;
        q.pya = ya * NX + gi; q.pyb = yb * NX + gi;
    };
    const bool has2 = (tid + 256 < PSZ);
    Idx q0, q1;
    mkidx(tid, q0);
    mkidx(has2 ? tid + 256 : tid, q1);

    // ---- issue global loads for level l (wave-uniform branches) ----
    auto loads = [&](int l, Raw& p, const Idx& q) {
        if (l >= 0 && l < NZ) {
            p.ph  = (l >= NZ - 1) ? Phis[q.pix] : Ps[l * PLN + q.pix];         // pad(l+1)
            p.phm = (l == 0) ? Phit[q.pix] : Ps[(l - 1) * PLN + q.pix];        // pad(l)
            p.mu  = Ms[l * PLN + q.pix];
            p.tht = Ts[l * PLN + q.pix];
            p.Uv  = Us[l * NY * NXU + q.uo];
            p.Vv  = Vs[l * (NY + 1) * NX + q.vo];
            p.mxa = Ms[l * PLN + q.pxa]; p.mxb = Ms[l * PLN + q.pxb];
            p.mya = Ms[l * PLN + q.pya]; p.myb = Ms[l * PLN + q.pyb];
            if (l < NZ - 1) {
                p.ph1 = (l + 1 >= NZ - 1) ? Phis[q.pix] : Ps[(l + 1) * PLN + q.pix];  // pad(l+2)
                p.mu1 = Ms[(l + 1) * PLN + q.pix];
                p.Wv  = Ws[l * PLN + q.pix];
            } else { p.ph1 = 0.f; p.mu1 = 1.f; p.Wv = 0.f; }
        } else {
            p.ph  = (l < 0) ? Phit[q.pix] : Phis[q.pix];
            p.phm = (l < 0) ? Pt[q.pix]   : Psrf[q.pix];   // pad-p boundary value
            p.ph1 = 0.f; p.mu = 0.f; p.mu1 = 1.f; p.tht = 0.f;
            p.Uv = 0.f; p.Vv = 0.f; p.Wv = 0.f;
            p.mxa = 1.f; p.mxb = 1.f; p.mya = 1.f; p.myb = 1.f;
        }
    };

    // ---- derive + write level l into rings ----
    auto derive = [&](int l, const Raw& p, int idx) {
        const int s3 = (l + 3) % 3, s2 = l & 1;
        float pv, th = 0.f, uv = 0.f, vv = 0.f, wv = 0.f, om = 0.f;
        float Uw = 0.f, Vw = 0.f, muw = 0.f;
        if (l >= 0 && l < NZ) {
            const float rmu = frcp(p.mu);
            const float al  = -(p.ph - p.phm) * RDZ * rmu;
            th = p.tht * rmu;
            pv = PREF * pow14(K_RP * th * frcp(al));
            uv = p.Uv * frcp(0.5f * (p.mxa + p.mxb));
            vv = p.Vv * frcp(0.5f * (p.mya + p.myb));
            Uw = p.Uv; Vw = p.Vv; muw = p.mu;
            if (l < NZ - 1) {
                const float al1 = -(p.ph1 - p.ph) * RDZ * frcp(p.mu1);
                const float mz  = 0.5f * (p.mu + p.mu1);
                wv = p.Wv * frcp(mz);
                om = -p.Wv * G * frcp(0.5f * (al + al1) * mz);
            }
        } else {
            pv = p.phm;   // P_t (l<0) or P_s (l>=NZ)
        }
        sPH[s3][idx] = p.ph; sP[s3][idx] = pv; sOM[s3][idx] = om;
        sMU[s2][idx] = muw;  sTH[s2][idx] = th;
        sUR[s2][idx] = Uw;   su_[s2][idx] = uv;
        sVR[s2][idx] = Vw;   sv_[s2][idx] = vv;
        sw_[s2][idx] = wv;
    };

    Raw r0, r1;
    // ---- prologue: direct fill of levels k0-1, k0 ----
    loads(k0 - 1, r0, q0); derive(k0 - 1, r0, tid);
    if (has2) { loads(k0 - 1, r1, q1); derive(k0 - 1, r1, tid + 256); }
    loads(k0, r0, q0); derive(k0, r0, tid);
    if (has2) { loads(k0, r1, q1); derive(k0, r1, tid + 256); }
    __syncthreads();

    // carried k-1 center registers (level k0-1)
    const int e0 = (k0 - 1) & 1;
    float th_m  = sTH[e0][ly * PW + lx];
    float u_m   = su_[e0][ly * PW + lx];
    float u_m_e = su_[e0][ly * PW + lx + 1];
    float v_m   = sv_[e0][ly * PW + lx];
    float v_m_e = sv_[e0][(ly + 1) * PW + lx];
    float w_m   = sw_[e0][ly * PW + lx];

    // stage loads for level k0+1
    loads(k0 + 1, r0, q0);
    if (has2) loads(k0 + 1, r1, q1);
    __syncthreads();

    for (int k = k0; k < k0 + KCH; ++k) {
        // write staged level k+1 into rings (pure VALU + LDS, loads already landed)
        derive(k + 1, r0, tid);
        if (has2) derive(k + 1, r1, tid + 256);
        __syncthreads();

        // issue next-next level loads; they complete under compute(k)
        if (k + 2 <= k0 + KCH) {
            loads(k + 2, r0, q0);
            if (has2) loads(k + 2, r1, q1);
        }

        // ---- ring aliases for compute(k) ----
        const float* PHa = sPH[(k + 2) % 3];  // level k-1
        const float* PHb = sPH[k % 3];        // level k
        const float* PHc = sPH[(k + 1) % 3];  // level k+1
        const float* Pa  = sP[(k + 2) % 3];
        const float* Pb  = sP[k % 3];
        const float* Pc  = sP[(k + 1) % 3];
        const float* Oa  = sOM[(k + 2) % 3];
        const float* Ob  = sOM[k % 3];
        const float* Oc  = sOM[(k + 1) % 3];
        const int e = k & 1, f = (k + 1) & 1;
        const float* MUe = sMU[e]; const float* MUf = sMU[f];
        const float* THe = sTH[e]; const float* THf = sTH[f];
        const float* URe = sUR[e]; const float* URf = sUR[f];
        const float* ue  = su_[e]; const float* uf  = su_[f];
        const float* VRe = sVR[e]; const float* VRf = sVR[f];
        const float* ve  = sv_[e]; const float* vf  = sv_[f];
        const float* we  = sw_[e]; const float* wf  = sw_[f];

        auto AT = [&](const float* p, int rr, int cc2) -> float { return p[rr * PW + cc2]; };
        auto ALx = [&](int rr, int cc2) -> float {   // alpha[k] at plane point
            return -(AT(PHb, rr, cc2) - AT(PHa, rr, cc2)) * RDZ * frcp(AT(MUe, rr, cc2));
        };

        // ---- R_U at staggered col cc (cells cc-1, cc) ----
        auto R_U_c = [&](int cc, float ukm) -> float {
            const float u0 = AT(ue, ly, cc), um = AT(ue, ly, cc - 1), up = AT(ue, ly, cc + 1);
            const float Uc = AT(URe, ly, cc), Um = AT(URe, ly, cc - 1), Up = AT(URe, ly, cc + 1);
            float r = -0.25f * ((Uc + Up) * (u0 + up) - (Um + Uc) * (um + u0)) * RDX;
            const float VBj  = 0.5f * (AT(VRe, ly, cc - 1) + AT(VRe, ly, cc));
            const float VBj1 = 0.5f * (AT(VRe, ly + 1, cc - 1) + AT(VRe, ly + 1, cc));
            const float uS = AT(ue, ly - 1, cc), uN = AT(ue, ly + 1, cc);
            r -= (VBj1 * 0.5f * (u0 + uN) - VBj * 0.5f * (uS + u0)) * RDY;
            const float OBk  = 0.5f * (AT(Oa, ly, cc - 1) + AT(Oa, ly, cc));
            const float OBk1 = 0.5f * (AT(Ob, ly, cc - 1) + AT(Ob, ly, cc));
            const float ukp = AT(uf, ly, cc);
            r -= (OBk1 * 0.5f * (u0 + ukp) - OBk * 0.5f * (ukm + u0)) * RDZ;
            const float mux = 0.5f * (AT(MUe, ly, cc - 1) + AT(MUe, ly, cc));
            const float alx = 0.5f * (ALx(ly, cc - 1) + ALx(ly, cc));
            const float dpx = (AT(Pb, ly, cc) - AT(Pb, ly, cc - 1)) * RDX;
            r -= mux * alx * dpx;
            const float pzk  = 0.25f * (AT(Pa, ly, cc - 1) + AT(Pb, ly, cc - 1)
                                      + AT(Pa, ly, cc)     + AT(Pb, ly, cc));
            const float pzk1 = 0.25f * (AT(Pb, ly, cc - 1) + AT(Pc, ly, cc - 1)
                                      + AT(Pb, ly, cc)     + AT(Pc, ly, cc));
            const float dpz = (pzk1 - pzk) * RDZ;
            const float pza = 0.5f * (AT(PHa, ly, cc - 1) + AT(PHb, ly, cc - 1));
            const float pzb = 0.5f * (AT(PHa, ly, cc)     + AT(PHb, ly, cc));
            r -= dpz * (pzb - pza) * RDX;
            return r;
        };

        // ---- R_V at staggered row rr (cells rr-1, rr) ----
        auto R_V_c = [&](int rr, float vkm) -> float {
            const float v0 = AT(ve, rr, lx), vm = AT(ve, rr - 1, lx), vp = AT(ve, rr + 1, lx);
            const float Vc = AT(VRe, rr, lx), Vm = AT(VRe, rr - 1, lx), Vp = AT(VRe, rr + 1, lx);
            float r = -0.25f * ((Vc + Vp) * (v0 + vp) - (Vm + Vc) * (vm + v0)) * RDY;
            const float UBi  = 0.5f * (AT(URe, rr - 1, lx)     + AT(URe, rr, lx));
            const float UBi1 = 0.5f * (AT(URe, rr - 1, lx + 1) + AT(URe, rr, lx + 1));
            const float vW = AT(ve, rr, lx - 1), vE = AT(ve, rr, lx + 1);
            r -= (UBi1 * 0.5f * (v0 + vE) - UBi * 0.5f * (vW + v0)) * RDX;
            const float OBk  = 0.5f * (AT(Oa, rr - 1, lx) + AT(Oa, rr, lx));
            const float OBk1 = 0.5f * (AT(Ob, rr - 1, lx) + AT(Ob, rr, lx));
            const float vkp = AT(vf, rr, lx);
            r -= (OBk1 * 0.5f * (v0 + vkp) - OBk * 0.5f * (vkm + v0)) * RDZ;
            const float muy = 0.5f * (AT(MUe, rr - 1, lx) + AT(MUe, rr, lx));
            const float aly = 0.5f * (ALx(rr - 1, lx) + ALx(rr, lx));
            const float dpy = (AT(Pb, rr, lx) - AT(Pb, rr - 1, lx)) * RDY;
            r -= muy * aly * dpy;
            const float pzk  = 0.25f * (AT(Pa, rr - 1, lx) + AT(Pb, rr - 1, lx)
                                      + AT(Pa, rr, lx)     + AT(Pb, rr, lx));
            const float pzk1 = 0.25f * (AT(Pb, rr - 1, lx) + AT(Pc, rr - 1, lx)
                                      + AT(Pb, rr, lx)     + AT(Pc, rr, lx));
            const float dpz = (pzk1 - pzk) * RDZ;
            const float pza = 0.5f * (AT(PHa, rr - 1, lx) + AT(PHb, rr - 1, lx));
            const float pzb = 0.5f * (AT(PHa, rr, lx)     + AT(PHb, rr, lx));
            r -= dpz * (pzb - pza) * RDY;
            return r;
        };

        // ===== R_Theta =====
        const float th0 = AT(THe, ly, lx);
        float rT = -(AT(URe, ly, lx + 1) * 0.5f * (th0 + AT(THe, ly, lx + 1))
                   - AT(URe, ly, lx)     * 0.5f * (AT(THe, ly, lx - 1) + th0)) * RDX
                   -(AT(VRe, ly + 1, lx) * 0.5f * (th0 + AT(THe, ly + 1, lx))
                   - AT(VRe, ly, lx)     * 0.5f * (AT(THe, ly - 1, lx) + th0)) * RDY;
        const float th_p = AT(THf, ly, lx);
        const float Hk  = AT(Oa, ly, lx) * 0.5f * (th_m + th0);
        const float Hk1 = AT(Ob, ly, lx) * 0.5f * (th0 + th_p);
        rT -= (Hk1 - Hk) * RDZ;

        // ===== R_Mu =====
        const float rM = -(AT(URe, ly, lx + 1) - AT(URe, ly, lx)) * RDX
                         -(AT(VRe, ly + 1, lx) - AT(VRe, ly, lx)) * RDY
                         -(AT(Ob, ly, lx) - AT(Oa, ly, lx)) * RDZ;

        // ===== stores (center) =====
        const int idc = (k * NY + j) * NX + i;
        To[idc] = T0[idc] + c * rT;
        Mo[idc] = M0[idc] + c * rM;
        const int idu = (k * NY + j) * NXU + i;
        Uo[idu] = U0[idu] + c * R_U_c(lx, u_m);
        const int idv = (k * (NY + 1) + j) * NX + i;
        Vo[idv] = V0[idv] + c * R_V_c(ly, v_m);

        // ===== R_W / R_Phi at half level k (k < NZ-1) =====
        if (k < NZ - 1) {
            const float w0 = AT(we, ly, lx);
            const float Uzi  = 0.5f * (AT(URe, ly, lx)     + AT(URf, ly, lx));
            const float Uzi1 = 0.5f * (AT(URe, ly, lx + 1) + AT(URf, ly, lx + 1));
            const float wW = AT(we, ly, lx - 1), wE = AT(we, ly, lx + 1);
            float rW = -(Uzi1 * 0.5f * (w0 + wE) - Uzi * 0.5f * (wW + w0)) * RDX;
            const float Vzj  = 0.5f * (AT(VRe, ly, lx)     + AT(VRf, ly, lx));
            const float Vzj1 = 0.5f * (AT(VRe, ly + 1, lx) + AT(VRf, ly + 1, lx));
            const float wS = AT(we, ly - 1, lx), wN = AT(we, ly + 1, lx);
            rW -= (Vzj1 * 0.5f * (w0 + wN) - Vzj * 0.5f * (wS + w0)) * RDY;
            const float OZk  = 0.5f * (AT(Oa, ly, lx) + AT(Ob, ly, lx));
            const float OZk1 = 0.5f * (AT(Ob, ly, lx) + AT(Oc, ly, lx));
            const float wkp = AT(wf, ly, lx);
            rW -= (OZk1 * 0.5f * (w0 + wkp) - OZk * 0.5f * (w_m + w0)) * RDZ;
            const float muz = 0.5f * (AT(MUe, ly, lx) + AT(MUf, ly, lx));
            rW += G * ((AT(Pc, ly, lx) - AT(Pb, ly, lx)) * RDZ - muz);

            const float ubz = 0.25f * (AT(ue, ly, lx) + AT(ue, ly, lx + 1)
                                     + AT(uf, ly, lx) + AT(uf, ly, lx + 1));
            const float dfx = (AT(PHb, ly, lx + 1) - AT(PHb, ly, lx - 1)) * (0.5f * RDX);
            const float vbz = 0.25f * (AT(ve, ly, lx) + AT(ve, ly + 1, lx)
                                     + AT(vf, ly, lx) + AT(vf, ly + 1, lx));
            const float dfy = (AT(PHb, ly + 1, lx) - AT(PHb, ly - 1, lx)) * (0.5f * RDY);
            const float rmuz = frcp(muz);
            const float om   = AT(Ob, ly, lx) * rmuz;
            const float dfz  = (AT(PHc, ly, lx) - AT(PHa, ly, lx)) * (0.5f * RDZ);
            const float rP = -ubz * dfx - vbz * dfy - om * dfz + G * w0;

            Wo[idc] = W0[idc] + c * rW;
            Po[idc] = P0[idc] + c * rP;
        }

        // ===== extra staggered col II=NX / row JJ=NY =====
        if (i == NX - 1) {
            Uo[idu + 1] = U0[idu + 1] + c * R_U_c(lx + 1, u_m_e);
        }
        if (j == NY - 1) {
            const int idv2 = (k * (NY + 1) + NY) * NX + i;
            Vo[idv2] = V0[idv2] + c * R_V_c(ly + 1, v_m_e);
        }

        // ===== capture k-1 carries for next level =====
        th_m  = th0;
        u_m   = AT(ue, ly, lx);
        u_m_e = AT(ue, ly, lx + 1);
        v_m   = AT(ve, ly, lx);
        v_m_e = AT(ve, ly + 1, lx);
        w_m   = AT(we, ly, lx);

        __syncthreads();
    }
}

} // anonymous namespace

extern "C" void kernel_launch(void* const* d_in, const int* in_sizes, int n_in,
                              void* d_out, int out_size, void* d_ws, size_t ws_size,
                              hipStream_t stream)
{
    (void)in_sizes; (void)n_in; (void)out_size; (void)ws_size;

    const float* U0   = (const float*)d_in[0];
    const float* V0   = (const float*)d_in[1];
    const float* W0   = (const float*)d_in[2];
    const float* T0   = (const float*)d_in[3];
    const float* M0   = (const float*)d_in[4];
    const float* P0   = (const float*)d_in[5];
    const float* Phit = (const float*)d_in[6];
    const float* Phis = (const float*)d_in[7];
    const float* Pt   = (const float*)d_in[8];
    const float* Psrf = (const float*)d_in[9];
    const int*   dtp  = (const int*)d_in[10];

    float* out = (float*)d_out;
    float* ws  = (float*)d_ws;

    float* outU = out;
    float* outV = outU + SZ_U;
    float* outW = outV + SZ_V;
    float* outT = outW + SZ_W;
    float* outM = outT + SZ_T;
    float* outP = outM + SZ_M;

    float* wsU = ws;
    float* wsV = wsU + SZ_U;
    float* wsW = wsV + SZ_V;
    float* wsT = wsW + SZ_W;
    float* wsM = wsT + SZ_T;
    float* wsP = wsM + SZ_M;

    const dim3 blk(TX, TY, 1);
    const dim3 grd(NX / TX, NY / TY, KSPLIT);

    const float coefs[3] = {1.0f / 3.0f, 0.5f, 1.0f};

    // stage ping-pong: d_in -> d_out -> ws -> d_out
    const float* sU[3] = {U0, outU, wsU};
    const float* sV[3] = {V0, outV, wsV};
    const float* sW[3] = {W0, outW, wsW};
    const float* sT[3] = {T0, outT, wsT};
    const float* sM[3] = {M0, outM, wsM};
    const float* sP_[3] = {P0, outP, wsP};
    float* oU[3] = {outU, wsU, outU};
    float* oV[3] = {outV, wsV, outV};
    float* oW[3] = {outW, wsW, outW};
    float* oT[3] = {outT, wsT, outT};
    float* oM[3] = {outM, wsM, outM};
    float* oP[3] = {outP, wsP, outP};

    for (int s = 0; s < 3; ++s) {
        rhs_tile<<<grd, blk, 0, stream>>>(
            sU[s], sV[s], sW[s], sT[s], sM[s], sP_[s],
            Phit, Phis, Pt, Psrf,
            U0, V0, W0, T0, M0, P0,
            oU[s], oV[s], oW[s], oT[s], oM[s], oP[s],
            dtp, coefs[s]);
    }
}

// Round 7
// 649.508 us; speedup vs baseline: 1.4671x; 1.4671x over previous
//
#include <hip/hip_runtime.h>

namespace {

constexpr int NX = 384, NY = 384, NZ = 48;
constexpr int NXU = NX + 1;
constexpr int PLN = NX * NY;
constexpr float RDX = 1.0f / 1000.0f;
constexpr float RDY = 1.0f / 1000.0f;
constexpr float RDZ = 49.0f;              // 1/DZ, DZ = 1/(NZ+1)
constexpr float PREF = 100000.0f, RD = 287.0f, G = 9.81f;
constexpr float K_RP = RD / PREF;

constexpr int SZ_U = NZ * NY * NXU;
constexpr int SZ_V = NZ * (NY + 1) * NX;
constexpr int SZ_W = (NZ - 1) * PLN;
constexpr int SZ_T = NZ * PLN;
constexpr int SZ_M = NZ * PLN;
constexpr int SZ_P = (NZ - 1) * PLN;

// tile geometry
constexpr int TX = 32, TY = 8;            // 256 threads
constexpr int PW = TX + 3;                // 35 (cols i0-1 .. i0+33)
constexpr int PH = TY + 3;                // 11 (rows j0-1 .. j0+9)
constexpr int PSZ = PW * PH;              // 385
constexpr int KCH = 12, KSPLIT = 4;

struct Idx { int pix, uo, vo, pxa, pxb, pya, pyb; };

__device__ __forceinline__ float frcp(float x) { return __builtin_amdgcn_rcpf(x); }
__device__ __forceinline__ float pow14(float x) {
    return __builtin_amdgcn_exp2f(1.4f * __builtin_amdgcn_logf(x));   // x^1.4 (base-2 HW ops)
}

__global__ __launch_bounds__(256, 3)
void rhs_tile(
    const float* __restrict__ Us, const float* __restrict__ Vs, const float* __restrict__ Ws,
    const float* __restrict__ Ts, const float* __restrict__ Ms, const float* __restrict__ Ps,
    const float* __restrict__ Phit, const float* __restrict__ Phis,
    const float* __restrict__ Pt,   const float* __restrict__ Psrf,
    const float* __restrict__ U0, const float* __restrict__ V0, const float* __restrict__ W0,
    const float* __restrict__ T0, const float* __restrict__ M0, const float* __restrict__ P0,
    float* __restrict__ Uo, float* __restrict__ Vo, float* __restrict__ Wo,
    float* __restrict__ To, float* __restrict__ Mo, float* __restrict__ Po,
    const int* __restrict__ dtp, float coef)
{
    const int tx = threadIdx.x, ty = threadIdx.y;
    const int tid = ty * TX + tx;
    const int i0 = blockIdx.x * TX;
    const int j0 = blockIdx.y * TY;
    const int k0 = blockIdx.z * KCH;
    const int i = i0 + tx, j = j0 + ty;
    const float c = coef * (float)(*dtp);
    const int ly = ty + 1, lx = tx + 1;

    // rings: 3-deep for Phi-pad / p-pad / Omega; 2-deep for the rest. 25 planes = 38.5 KB
    __shared__ float sPH[3][PSZ], sP[3][PSZ], sOM[3][PSZ];
    __shared__ float sAL[2][PSZ], sMU[2][PSZ], sTH[2][PSZ], sUR[2][PSZ], su_[2][PSZ],
                     sVR[2][PSZ], sv_[2][PSZ], sw_[2][PSZ];

    auto mkidx = [&](int idx, Idx& q) {
        const int r  = idx / PW;
        const int cc = idx - r * PW;
        int gj = j0 - 1 + r;  if (gj < 0) gj += NY; else if (gj >= NY) gj -= NY;
        int gi = i0 - 1 + cc; if (gi < 0) gi += NX; else if (gi >= NX) gi -= NX;
        int gII = i0 - 1 + cc; if (gII < 0) gII += NX + 1; else if (gII > NX) gII -= NX + 1;
        int gJJ = j0 - 1 + r;  if (gJJ < 0) gJJ += NY + 1; else if (gJJ > NY) gJJ -= NY + 1;
        q.pix = gj * NX + gi;
        q.uo  = gj * NXU + gII;
        q.vo  = gJJ * NX + gi;
        const int xa = (gII == 0)  ? NX - 1 : gII - 1;
        const int xb = (gII == NX) ? 0      : gII;
        const int ya = (gJJ == 0)  ? NY - 1 : gJJ - 1;
        const int yb = (gJJ == NY) ? 0      : gJJ;
        q.pxa = gj * NX + xa; q.pxb = gj * NX + xb;
        q.pya = ya * NX + gi; q.pyb = yb * NX + gi;
    };
    const bool has2 = (tid + 256 < PSZ);
    Idx q0, q1;
    mkidx(tid, q0);
    mkidx(has2 ? tid + 256 : tid, q1);

    // ---- load + derive one plane point at level l; registers live only inside ----
    auto fill1 = [&](int l, const Idx& q, int idx) {
        const int s3 = (l + 3) % 3, s2 = l & 1;
        float phv, pv, al = 0.f, th = 0.f, uv = 0.f, vv = 0.f, wv = 0.f, om = 0.f;
        float Uw = 0.f, Vw = 0.f, muw = 0.f;
        if (l >= 0 && l < NZ) {
            phv = (l >= NZ - 1) ? Phis[q.pix] : Ps[l * PLN + q.pix];          // PHIP(l+1)
            const float phm = (l == 0) ? Phit[q.pix] : Ps[(l - 1) * PLN + q.pix]; // PHIP(l)
            const float mu  = Ms[l * PLN + q.pix];
            const float rmu = frcp(mu);
            al = -(phv - phm) * RDZ * rmu;
            th = Ts[l * PLN + q.pix] * rmu;
            pv = PREF * pow14(K_RP * th * frcp(al));
            const float Uv = Us[l * NY * NXU + q.uo];
            uv = Uv * frcp(0.5f * (Ms[l * PLN + q.pxa] + Ms[l * PLN + q.pxb]));
            const float Vv = Vs[l * (NY + 1) * NX + q.vo];
            vv = Vv * frcp(0.5f * (Ms[l * PLN + q.pya] + Ms[l * PLN + q.pyb]));
            Uw = Uv; Vw = Vv; muw = mu;
            if (l < NZ - 1) {
                const float mu1 = Ms[(l + 1) * PLN + q.pix];
                const float Wv  = Ws[l * PLN + q.pix];
                const float ph1 = (l + 1 >= NZ - 1) ? Phis[q.pix] : Ps[(l + 1) * PLN + q.pix];
                const float al1 = -(ph1 - phv) * RDZ * frcp(mu1);
                const float mz  = 0.5f * (mu + mu1);
                wv = Wv * frcp(mz);
                om = -Wv * G * frcp(0.5f * (al + al1) * mz);
            }
        } else {
            phv = (l < 0) ? Phit[q.pix] : Phis[q.pix];
            pv  = (l < 0) ? Pt[q.pix]   : Psrf[q.pix];   // pad-p boundary value
        }
        sPH[s3][idx] = phv; sP[s3][idx] = pv; sOM[s3][idx] = om;
        sAL[s2][idx] = al;  sMU[s2][idx] = muw; sTH[s2][idx] = th;
        sUR[s2][idx] = Uw;  su_[s2][idx] = uv;
        sVR[s2][idx] = Vw;  sv_[s2][idx] = vv;
        sw_[s2][idx] = wv;
    };
    auto fill = [&](int l) {
        fill1(l, q0, tid);
        if (has2) fill1(l, q1, tid + 256);
    };

    // ---- prologue ----
    fill(k0 - 1);
    fill(k0);
    __syncthreads();

    // carried k-1 center registers (level k0-1)
    const int e0 = (k0 - 1) & 1;
    float th_m  = sTH[e0][ly * PW + lx];
    float u_m   = su_[e0][ly * PW + lx];
    float u_m_e = su_[e0][ly * PW + lx + 1];
    float v_m   = sv_[e0][ly * PW + lx];
    float v_m_e = sv_[e0][(ly + 1) * PW + lx];
    float w_m   = sw_[e0][ly * PW + lx];

    for (int k = k0; k < k0 + KCH; ++k) {
        fill(k + 1);
        __syncthreads();

        // ---- ring aliases for compute(k) ----
        const float* PHa = sPH[(k + 2) % 3];  // level k-1  (holds PHIP(k))
        const float* PHb = sPH[k % 3];        // level k    (holds PHIP(k+1))
        const float* PHc = sPH[(k + 1) % 3];  // level k+1  (holds PHIP(k+2))
        const float* Pa  = sP[(k + 2) % 3];
        const float* Pb  = sP[k % 3];
        const float* Pc  = sP[(k + 1) % 3];
        const float* Oa  = sOM[(k + 2) % 3];  // OMP(k)
        const float* Ob  = sOM[k % 3];        // OMP(k+1)
        const float* Oc  = sOM[(k + 1) % 3];  // OMP(k+2)
        const int e = k & 1, f = (k + 1) & 1;
        const float* ALe = sAL[e];
        const float* MUe = sMU[e]; const float* MUf = sMU[f];
        const float* THe = sTH[e]; const float* THf = sTH[f];
        const float* URe = sUR[e]; const float* URf = sUR[f];
        const float* ue  = su_[e]; const float* uf  = su_[f];
        const float* VRe = sVR[e]; const float* VRf = sVR[f];
        const float* ve  = sv_[e]; const float* vf  = sv_[f];
        const float* we  = sw_[e]; const float* wf  = sw_[f];

        auto AT = [&](const float* p, int rr, int cc2) -> float { return p[rr * PW + cc2]; };

        // ---- R_U at staggered col cc (cells cc-1, cc) ----
        auto R_U_c = [&](int cc, float ukm) -> float {
            const float u0 = AT(ue, ly, cc), um = AT(ue, ly, cc - 1), up = AT(ue, ly, cc + 1);
            const float Uc = AT(URe, ly, cc), Um = AT(URe, ly, cc - 1), Up = AT(URe, ly, cc + 1);
            float r = -0.25f * ((Uc + Up) * (u0 + up) - (Um + Uc) * (um + u0)) * RDX;
            const float VBj  = 0.5f * (AT(VRe, ly, cc - 1) + AT(VRe, ly, cc));
            const float VBj1 = 0.5f * (AT(VRe, ly + 1, cc - 1) + AT(VRe, ly + 1, cc));
            const float uS = AT(ue, ly - 1, cc), uN = AT(ue, ly + 1, cc);
            r -= (VBj1 * 0.5f * (u0 + uN) - VBj * 0.5f * (uS + u0)) * RDY;
            const float OBk  = 0.5f * (AT(Oa, ly, cc - 1) + AT(Oa, ly, cc));
            const float OBk1 = 0.5f * (AT(Ob, ly, cc - 1) + AT(Ob, ly, cc));
            const float ukp = AT(uf, ly, cc);
            r -= (OBk1 * 0.5f * (u0 + ukp) - OBk * 0.5f * (ukm + u0)) * RDZ;
            const float mux = 0.5f * (AT(MUe, ly, cc - 1) + AT(MUe, ly, cc));
            const float alx = 0.5f * (AT(ALe, ly, cc - 1) + AT(ALe, ly, cc));
            const float dpx = (AT(Pb, ly, cc) - AT(Pb, ly, cc - 1)) * RDX;
            r -= mux * alx * dpx;
            const float pzk  = 0.25f * (AT(Pa, ly, cc - 1) + AT(Pb, ly, cc - 1)
                                      + AT(Pa, ly, cc)     + AT(Pb, ly, cc));
            const float pzk1 = 0.25f * (AT(Pb, ly, cc - 1) + AT(Pc, ly, cc - 1)
                                      + AT(Pb, ly, cc)     + AT(Pc, ly, cc));
            const float dpz = (pzk1 - pzk) * RDZ;
            const float pza = 0.5f * (AT(PHa, ly, cc - 1) + AT(PHb, ly, cc - 1));
            const float pzb = 0.5f * (AT(PHa, ly, cc)     + AT(PHb, ly, cc));
            r -= dpz * (pzb - pza) * RDX;
            return r;
        };

        // ---- R_V at staggered row rr (cells rr-1, rr) ----
        auto R_V_c = [&](int rr, float vkm) -> float {
            const float v0 = AT(ve, rr, lx), vm = AT(ve, rr - 1, lx), vp = AT(ve, rr + 1, lx);
            const float Vc = AT(VRe, rr, lx), Vm = AT(VRe, rr - 1, lx), Vp = AT(VRe, rr + 1, lx);
            float r = -0.25f * ((Vc + Vp) * (v0 + vp) - (Vm + Vc) * (vm + v0)) * RDY;
            const float UBi  = 0.5f * (AT(URe, rr - 1, lx)     + AT(URe, rr, lx));
            const float UBi1 = 0.5f * (AT(URe, rr - 1, lx + 1) + AT(URe, rr, lx + 1));
            const float vW = AT(ve, rr, lx - 1), vE = AT(ve, rr, lx + 1);
            r -= (UBi1 * 0.5f * (v0 + vE) - UBi * 0.5f * (vW + v0)) * RDX;
            const float OBk  = 0.5f * (AT(Oa, rr - 1, lx) + AT(Oa, rr, lx));
            const float OBk1 = 0.5f * (AT(Ob, rr - 1, lx) + AT(Ob, rr, lx));
            const float vkp = AT(vf, rr, lx);
            r -= (OBk1 * 0.5f * (v0 + vkp) - OBk * 0.5f * (vkm + v0)) * RDZ;
            const float muy = 0.5f * (AT(MUe, rr - 1, lx) + AT(MUe, rr, lx));
            const float aly = 0.5f * (AT(ALe, rr - 1, lx) + AT(ALe, rr, lx));
            const float dpy = (AT(Pb, rr, lx) - AT(Pb, rr - 1, lx)) * RDY;
            r -= muy * aly * dpy;
            const float pzk  = 0.25f * (AT(Pa, rr - 1, lx) + AT(Pb, rr - 1, lx)
                                      + AT(Pa, rr, lx)     + AT(Pb, rr, lx));
            const float pzk1 = 0.25f * (AT(Pb, rr - 1, lx) + AT(Pc, rr - 1, lx)
                                      + AT(Pb, rr, lx)     + AT(Pc, rr, lx));
            const float dpz = (pzk1 - pzk) * RDZ;
            const float pza = 0.5f * (AT(PHa, rr - 1, lx) + AT(PHb, rr - 1, lx));
            const float pzb = 0.5f * (AT(PHa, rr, lx)     + AT(PHb, rr, lx));
            r -= dpz * (pzb - pza) * RDY;
            return r;
        };

        // ===== R_Theta =====
        const float th0 = AT(THe, ly, lx);
        float rT = -(AT(URe, ly, lx + 1) * 0.5f * (th0 + AT(THe, ly, lx + 1))
                   - AT(URe, ly, lx)     * 0.5f * (AT(THe, ly, lx - 1) + th0)) * RDX
                   -(AT(VRe, ly + 1, lx) * 0.5f * (th0 + AT(THe, ly + 1, lx))
                   - AT(VRe, ly, lx)     * 0.5f * (AT(THe, ly - 1, lx) + th0)) * RDY;
        const float th_p = AT(THf, ly, lx);
        const float Hk  = AT(Oa, ly, lx) * 0.5f * (th_m + th0);
        const float Hk1 = AT(Ob, ly, lx) * 0.5f * (th0 + th_p);
        rT -= (Hk1 - Hk) * RDZ;

        // ===== R_Mu =====
        const float rM = -(AT(URe, ly, lx + 1) - AT(URe, ly, lx)) * RDX
                         -(AT(VRe, ly + 1, lx) - AT(VRe, ly, lx)) * RDY
                         -(AT(Ob, ly, lx) - AT(Oa, ly, lx)) * RDZ;

        // ===== stores (center) =====
        const int idc = (k * NY + j) * NX + i;
        To[idc] = T0[idc] + c * rT;
        Mo[idc] = M0[idc] + c * rM;
        const int idu = (k * NY + j) * NXU + i;
        Uo[idu] = U0[idu] + c * R_U_c(lx, u_m);
        const int idv = (k * (NY + 1) + j) * NX + i;
        Vo[idv] = V0[idv] + c * R_V_c(ly, v_m);

        // ===== R_W / R_Phi at half level k (k < NZ-1) =====
        if (k < NZ - 1) {
            const float w0 = AT(we, ly, lx);
            const float Uzi  = 0.5f * (AT(URe, ly, lx)     + AT(URf, ly, lx));
            const float Uzi1 = 0.5f * (AT(URe, ly, lx + 1) + AT(URf, ly, lx + 1));
            const float wW = AT(we, ly, lx - 1), wE = AT(we, ly, lx + 1);
            float rW = -(Uzi1 * 0.5f * (w0 + wE) - Uzi * 0.5f * (wW + w0)) * RDX;
            const float Vzj  = 0.5f * (AT(VRe, ly, lx)     + AT(VRf, ly, lx));
            const float Vzj1 = 0.5f * (AT(VRe, ly + 1, lx) + AT(VRf, ly + 1, lx));
            const float wS = AT(we, ly - 1, lx), wN = AT(we, ly + 1, lx);
            rW -= (Vzj1 * 0.5f * (w0 + wN) - Vzj * 0.5f * (wS + w0)) * RDY;
            const float OZk  = 0.5f * (AT(Oa, ly, lx) + AT(Ob, ly, lx));
            const float OZk1 = 0.5f * (AT(Ob, ly, lx) + AT(Oc, ly, lx));
            const float wkp = AT(wf, ly, lx);
            rW -= (OZk1 * 0.5f * (w0 + wkp) - OZk * 0.5f * (w_m + w0)) * RDZ;
            const float muz = 0.5f * (AT(MUe, ly, lx) + AT(MUf, ly, lx));
            rW += G * ((AT(Pc, ly, lx) - AT(Pb, ly, lx)) * RDZ - muz);

            const float ubz = 0.25f * (AT(ue, ly, lx) + AT(ue, ly, lx + 1)
                                     + AT(uf, ly, lx) + AT(uf, ly, lx + 1));
            const float dfx = (AT(PHb, ly, lx + 1) - AT(PHb, ly, lx - 1)) * (0.5f * RDX);
            const float vbz = 0.25f * (AT(ve, ly, lx) + AT(ve, ly + 1, lx)
                                     + AT(vf, ly, lx) + AT(vf, ly + 1, lx));
            const float dfy = (AT(PHb, ly + 1, lx) - AT(PHb, ly - 1, lx)) * (0.5f * RDY);
            const float rmuz = frcp(muz);
            const float om   = AT(Ob, ly, lx) * rmuz;
            const float dfz  = (AT(PHc, ly, lx) - AT(PHa, ly, lx)) * (0.5f * RDZ);
            const float rP = -ubz * dfx - vbz * dfy - om * dfz + G * w0;

            Wo[idc] = W0[idc] + c * rW;
            Po[idc] = P0[idc] + c * rP;
        }

        // ===== extra staggered col II=NX / row JJ=NY =====
        if (i == NX - 1) {
            Uo[idu + 1] = U0[idu + 1] + c * R_U_c(lx + 1, u_m_e);
        }
        if (j == NY - 1) {
            const int idv2 = (k * (NY + 1) + NY) * NX + i;
            Vo[idv2] = V0[idv2] + c * R_V_c(ly + 1, v_m_e);
        }

        // ===== capture k-1 carries for next level =====
        th_m  = th0;
        u_m   = AT(ue, ly, lx);
        u_m_e = AT(ue, ly, lx + 1);
        v_m   = AT(ve, ly, lx);
        v_m_e = AT(ve, ly + 1, lx);
        w_m   = AT(we, ly, lx);

        __syncthreads();
    }
}

} // anonymous namespace

extern "C" void kernel_launch(void* const* d_in, const int* in_sizes, int n_in,
                              void* d_out, int out_size, void* d_ws, size_t ws_size,
                              hipStream_t stream)
{
    (void)in_sizes; (void)n_in; (void)out_size; (void)ws_size;

    const float* U0   = (const float*)d_in[0];
    const float* V0   = (const float*)d_in[1];
    const float* W0   = (const float*)d_in[2];
    const float* T0   = (const float*)d_in[3];
    const float* M0   = (const float*)d_in[4];
    const float* P0   = (const float*)d_in[5];
    const float* Phit = (const float*)d_in[6];
    const float* Phis = (const float*)d_in[7];
    const float* Pt   = (const float*)d_in[8];
    const float* Psrf = (const float*)d_in[9];
    const int*   dtp  = (const int*)d_in[10];

    float* out = (float*)d_out;
    float* ws  = (float*)d_ws;

    float* outU = out;
    float* outV = outU + SZ_U;
    float* outW = outV + SZ_V;
    float* outT = outW + SZ_W;
    float* outM = outT + SZ_T;
    float* outP = outM + SZ_M;

    float* wsU = ws;
    float* wsV = wsU + SZ_U;
    float* wsW = wsV + SZ_V;
    float* wsT = wsW + SZ_W;
    float* wsM = wsT + SZ_T;
    float* wsP = wsM + SZ_M;

    const dim3 blk(TX, TY, 1);
    const dim3 grd(NX / TX, NY / TY, KSPLIT);

    const float coefs[3] = {1.0f / 3.0f, 0.5f, 1.0f};

    // stage ping-pong: d_in -> d_out -> ws -> d_out
    const float* sU[3] = {U0, outU, wsU};
    const float* sV[3] = {V0, outV, wsV};
    const float* sW[3] = {W0, outW, wsW};
    const float* sT[3] = {T0, outT, wsT};
    const float* sM[3] = {M0, outM, wsM};
    const float* sP_[3] = {P0, outP, wsP};
    float* oU[3] = {outU, wsU, outU};
    float* oV[3] = {outV, wsV, outV};
    float* oW[3] = {outW, wsW, outW};
    float* oT[3] = {outT, wsT, outT};
    float* oM[3] = {outM, wsM, outM};
    float* oP[3] = {outP, wsP, outP};

    for (int s = 0; s < 3; ++s) {
        rhs_tile<<<grd, blk, 0, stream>>>(
            sU[s], sV[s], sW[s], sT[s], sM[s], sP_[s],
            Phit, Phis, Pt, Psrf,
            U0, V0, W0, T0, M0, P0,
            oU[s], oV[s], oW[s], oT[s], oM[s], oP[s],
            dtp, coefs[s]);
    }
}